// Round 5
// baseline (460.593 us; speedup 1.0000x reference)
//
#include <hip/hip_runtime.h>
#include <hip/hip_cooperative_groups.h>
#include <hip/hip_bf16.h>
#include <math.h>

namespace cg = cooperative_groups;

#define SEQ 8192
#define DIN 512
#define DH  64
#define SG  8                 // grid 512 = 2 blocks/CU exact (3-buffer LDS)
#define CHUNK (SEQ / SG)      // 1024 K-rows per flash block
#define BK  64                // K/V rows per iteration
#define NIT (CHUNK / BK)      // 16 iterations (compile-time)
#define LDK 64                // flash LDS row stride (bf16): 128B, XOR-swizzled
#define SXP 516               // padded fp32 x row stride (pgemm)
#define SMEM_BYTES 73728      // 3*24576: flash triple-buffer; pgemm uses 33024

typedef float f32x4 __attribute__((ext_vector_type(4)));
typedef short short8 __attribute__((ext_vector_type(8)));
typedef ushort us4 __attribute__((ext_vector_type(4)));

static __device__ __forceinline__ ushort bf16_of(float v) {
  __hip_bfloat16 h = __float2bfloat16(v);
  return *reinterpret_cast<ushort*>(&h);
}
static __device__ __forceinline__ float f_of_bf16(ushort u) {
  __hip_bfloat16 h;
  *reinterpret_cast<ushort*>(&h) = u;
  return __bfloat162float(h);
}
static __device__ __forceinline__ f32x4 mfma16(short8 a, short8 b, f32x4 c) {
  return __builtin_amdgcn_mfma_f32_16x16x32_bf16(a, b, c, 0, 0, 0);
}
static __device__ __forceinline__ uint pack_bf16(float a, float b) {
  __hip_bfloat162 h2 = __float22bfloat162_rn(make_float2(a, b));
  return *reinterpret_cast<uint*>(&h2);
}
// K-row permutation (R12-proven): physical row p -> LDS slot, chosen so the
// S^T C-layout ownership coincides with the PV B-operand k-ownership,
// making the P^T fragment pure register renaming.
static __device__ __forceinline__ int slot_of(int p) {
  return ((((p >> 2) & 1) * 2 + (p >> 5)) << 4) | (((p >> 3) & 3) << 2) | (p & 3);
}
// R13-proven XOR chunk swizzle (bank conflicts 3.1M -> 0, measured).
static __device__ __forceinline__ int swz(int row, int col) {
  return col ^ ((row & 7) << 3);
}
// R16-proven lgkm-only barrier (global prefetch loads stay in flight).
static __device__ __forceinline__ void bar_lgkm() {
  asm volatile("s_waitcnt lgkmcnt(0)" ::: "memory");
  __builtin_amdgcn_s_barrier();
}

// ---------------------------------------------------------------------------
// Phase 1 (pgemm v4 logic, UNCHANGED from R16; now a device function).
// ---------------------------------------------------------------------------
static __device__ void pgemm_phase(
    char* smem,
    const float* __restrict__ x,  const float* __restrict__ Wq,
    const float* __restrict__ Wk, const float* __restrict__ Wv,
    ushort* __restrict__ Qh, ushort* __restrict__ Ql,
    ushort* __restrict__ Kh, ushort* __restrict__ Kl,
    ushort* __restrict__ Vt) {
  float (*sx)[SXP] = reinterpret_cast<float (*)[SXP]>(smem);   // 33 KB
  float* mb = reinterpret_cast<float*>(smem);                  // merge alias

  const int tid = threadIdx.x;
  const int wv = tid >> 6, lane = tid & 63;
  const int ln = lane & 15, qd = lane >> 4;
  const int rb = blockIdx.x * 16;

  {
    const float4* xg = reinterpret_cast<const float4*>(x + (size_t)rb * DIN);
#pragma unroll
    for (int j = 0; j < 8; ++j) {
      const int idx = tid + 256 * j;
      const int row = idx >> 7;
      const int col = (idx & 127) * 4;
      *reinterpret_cast<float4*>(&sx[row][col]) = xg[idx];
    }
  }
  __syncthreads();

  f32x4 acc[3][4];
#pragma unroll
  for (int m = 0; m < 3; ++m)
#pragma unroll
    for (int nt = 0; nt < 4; ++nt)
#pragma unroll
      for (int i = 0; i < 4; ++i) acc[m][nt][i] = 0.f;

  const int kb = wv * 128;
  const int wbase = (kb + qd * 8) * 64 + ln;

  float wf[2][32];
#define LDW(kt_, m_, buf_)                                                     \
  do {                                                                         \
    const float* W_ = ((m_) == 0) ? Wq : (((m_) == 1) ? Wk : Wv);              \
    const int o_ = wbase + (kt_) * 32 * 64;                                    \
    _Pragma("unroll") for (int nt = 0; nt < 4; ++nt)                           \
      _Pragma("unroll") for (int j = 0; j < 8; ++j)                            \
        wf[buf_][nt * 8 + j] = W_[o_ + j * 64 + nt * 16];                      \
  } while (0)

  LDW(0, 0, 0);
#pragma unroll
  for (int kt = 0; kt < 4; ++kt) {
    const int k0 = kb + kt * 32;
    float xs[8];
    *reinterpret_cast<float4*>(xs) =
        *reinterpret_cast<const float4*>(&sx[ln][k0 + qd * 8]);
    *reinterpret_cast<float4*>(xs + 4) =
        *reinterpret_cast<const float4*>(&sx[ln][k0 + qd * 8 + 4]);
    ushort ah[8] __attribute__((aligned(16)));
    ushort al[8] __attribute__((aligned(16)));
#pragma unroll
    for (int j = 0; j < 8; ++j) {
      const ushort h = bf16_of(xs[j]);
      ah[j] = h;
      al[j] = bf16_of(xs[j] - f_of_bf16(h));
    }
    const short8 Ah = *reinterpret_cast<short8*>(ah);
    const short8 Al = *reinterpret_cast<short8*>(al);
#pragma unroll
    for (int m = 0; m < 3; ++m) {
      const int g = kt * 3 + m;               // compile-time (unrolled)
      const int buf = g & 1;
      if (g < 11) {
        const int gn = g + 1;
        LDW(gn / 3, gn % 3, buf ^ 1);         // prefetch next group's W fp32
      }
      const float scale = (m == 0) ? 0.125f * 1.44269504088896f : 1.0f;
#pragma unroll
      for (int nt = 0; nt < 4; ++nt) {
        ushort bh8[8] __attribute__((aligned(16)));
        ushort bl8[8] __attribute__((aligned(16)));
#pragma unroll
        for (int j = 0; j < 8; ++j) {
          const float v = wf[buf][nt * 8 + j] * scale;
          const ushort h = bf16_of(v);
          bh8[j] = h;
          bl8[j] = bf16_of(v - f_of_bf16(h));
        }
        const short8 bh = *reinterpret_cast<short8*>(bh8);
        const short8 bl = *reinterpret_cast<short8*>(bl8);
        acc[m][nt] = mfma16(Ah, bh, acc[m][nt]);
        acc[m][nt] = mfma16(Ah, bl, acc[m][nt]);
        acc[m][nt] = mfma16(Al, bh, acc[m][nt]);
      }
    }
  }
#undef LDW

  const int eidx = (qd * 4) * 64 + ln;
  __syncthreads();
  if (wv >= 2) {
    float* b = mb + (size_t)(wv - 2) * 3072;
#pragma unroll
    for (int m = 0; m < 3; ++m)
#pragma unroll
      for (int nt = 0; nt < 4; ++nt)
#pragma unroll
        for (int r = 0; r < 4; ++r)
          b[m * 1024 + eidx + r * 64 + nt * 16] = acc[m][nt][r];
  }
  __syncthreads();
  if (wv < 2) {
    const float* b = mb + (size_t)wv * 3072;
#pragma unroll
    for (int m = 0; m < 3; ++m)
#pragma unroll
      for (int nt = 0; nt < 4; ++nt)
#pragma unroll
        for (int r = 0; r < 4; ++r)
          acc[m][nt][r] += b[m * 1024 + eidx + r * 64 + nt * 16];
  }
  __syncthreads();
  if (wv == 1) {
#pragma unroll
    for (int m = 0; m < 3; ++m)
#pragma unroll
      for (int nt = 0; nt < 4; ++nt)
#pragma unroll
        for (int r = 0; r < 4; ++r)
          mb[m * 1024 + eidx + r * 64 + nt * 16] = acc[m][nt][r];
  }
  __syncthreads();
  if (wv == 0) {
#pragma unroll
    for (int m = 0; m < 3; ++m)
#pragma unroll
      for (int nt = 0; nt < 4; ++nt)
#pragma unroll
        for (int r = 0; r < 4; ++r)
          acc[m][nt][r] += mb[m * 1024 + eidx + r * 64 + nt * 16];

#pragma unroll
    for (int m = 0; m < 2; ++m) {
      ushort* H = (m == 0) ? Qh : Kh;
      ushort* L = (m == 0) ? Ql : Kl;
#pragma unroll
      for (int nt = 0; nt < 4; ++nt)
#pragma unroll
        for (int r = 0; r < 4; ++r) {
          const float v = acc[m][nt][r];
          const int row = rb + qd * 4 + r;
          const int col = nt * 16 + ln;
          const ushort h = bf16_of(v);
          H[(size_t)row * DH + col] = h;
          L[(size_t)row * DH + col] = bf16_of(v - f_of_bf16(h));
        }
    }
#pragma unroll
    for (int nt = 0; nt < 4; ++nt) {
      ushort vp[4] __attribute__((aligned(8)));
#pragma unroll
      for (int r = 0; r < 4; ++r) vp[r] = bf16_of(acc[2][nt][r]);
      *reinterpret_cast<us4*>(Vt + (size_t)(nt * 16 + ln) * SEQ + rb + qd * 4) =
          *reinterpret_cast<us4*>(vp);
    }
  }
}

// ---------------------------------------------------------------------------
// Phase 2 (flash v9 logic, UNCHANGED from R16; now a device function).
// ---------------------------------------------------------------------------
static __device__ void flash_phase(
    char* smem,
    const ushort* __restrict__ Qh, const ushort* __restrict__ Ql,
    const ushort* __restrict__ Kh, const ushort* __restrict__ Kl,
    const ushort* __restrict__ Vt,
    ushort* __restrict__ Opart, float* __restrict__ Mpart,
    float* __restrict__ Lpart) {
  ushort (*sKh)[BK][LDK] = reinterpret_cast<ushort (*)[BK][LDK]>(smem);
  ushort (*sKl)[BK][LDK] = reinterpret_cast<ushort (*)[BK][LDK]>(smem + 24576);
  ushort (*sVt)[DH][LDK] = reinterpret_cast<ushort (*)[DH][LDK]>(smem + 49152);

  const int tid  = threadIdx.x;
  const int wv   = tid >> 6;
  const int lane = tid & 63;
  const int ln   = lane & 15;
  const int qd   = lane >> 4;
  const int bid  = blockIdx.x;
  const int sg   = bid & (SG - 1);
  const int qt   = bid >> 3;            // 0..63 (128-row Q tiles)
  const int qrow0  = qt * 128 + wv * 32;   // set s adds s*16
  const int k0base = sg * CHUNK;

  const int r0 = tid >> 3, g0 = (tid & 7) * 8;
  const int r1 = r0 + 32,  g1 = g0;
  const int sr0 = slot_of(r0), sr1 = slot_of(r1);   // permuted K slots

  const ushort one_u = (ln == 0) ? (ushort)0x3F80 : (ushort)0;
  short8 afr1;
#pragma unroll
  for (int j = 0; j < 8; ++j) afr1[j] = (short)one_u;

  short8 bqh[2][2], bql[2][2];
#pragma unroll
  for (int s = 0; s < 2; ++s)
#pragma unroll
    for (int kt = 0; kt < 2; ++kt) {
      bqh[s][kt] = *reinterpret_cast<const short8*>(
          Qh + (size_t)(qrow0 + s * 16 + ln) * DH + kt * 32 + qd * 8);
      bql[s][kt] = *reinterpret_cast<const short8*>(
          Ql + (size_t)(qrow0 + s * 16 + ln) * DH + kt * 32 + qd * 8);
    }

  f32x4 accO[2][4], accL[2];
  float m_run[2] = {-INFINITY, -INFINITY};
#pragma unroll
  for (int s = 0; s < 2; ++s) {
#pragma unroll
    for (int nt = 0; nt < 4; ++nt)
#pragma unroll
      for (int i = 0; i < 4; ++i) accO[s][nt][i] = 0.f;
#pragma unroll
    for (int i = 0; i < 4; ++i) accL[s][i] = 0.f;
  }
  const f32x4 z4 = {0.f, 0.f, 0.f, 0.f};   // persistent zero C-operand

  f32x4 accSA[2][4], accSB[2][4];          // 2-deep S pipeline

  uint4 pk0, pk1, pl0, pl1, pv0, pv1;
#define LOAD_TILES(k0_)                                                        \
  do {                                                                         \
    pk0 = *reinterpret_cast<const uint4*>(Kh + (size_t)((k0_) + r0) * DH + g0);\
    pk1 = *reinterpret_cast<const uint4*>(Kh + (size_t)((k0_) + r1) * DH + g1);\
    pl0 = *reinterpret_cast<const uint4*>(Kl + (size_t)((k0_) + r0) * DH + g0);\
    pl1 = *reinterpret_cast<const uint4*>(Kl + (size_t)((k0_) + r1) * DH + g1);\
    pv0 = *reinterpret_cast<const uint4*>(Vt + (size_t)r0 * SEQ + (k0_) + g0); \
    pv1 = *reinterpret_cast<const uint4*>(Vt + (size_t)r1 * SEQ + (k0_) + g1); \
  } while (0)
#define STORE_TILES(b_)                                                        \
  do {                                                                         \
    *reinterpret_cast<uint4*>(&sKh[b_][sr0][swz(sr0, g0)]) = pk0;              \
    *reinterpret_cast<uint4*>(&sKh[b_][sr1][swz(sr1, g1)]) = pk1;              \
    *reinterpret_cast<uint4*>(&sKl[b_][sr0][swz(sr0, g0)]) = pl0;              \
    *reinterpret_cast<uint4*>(&sKl[b_][sr1][swz(sr1, g1)]) = pl1;              \
    *reinterpret_cast<uint4*>(&sVt[b_][r0][swz(r0, g0)])   = pv0;              \
    *reinterpret_cast<uint4*>(&sVt[b_][r1][swz(r1, g1)])   = pv1;              \
  } while (0)

  // QK^T of one tile from buffer b_ into ACC (hi*hi + hi*lo + lo*hi).
#define QK_PHASE(ACC, b_)                                                      \
  do {                                                                         \
    _Pragma("unroll") for (int nt = 0; nt < 4; ++nt) {                         \
      const int kr = nt * 16 + ln;                                             \
      const short8 kh0 = *reinterpret_cast<const short8*>(                     \
          &sKh[b_][kr][swz(kr, qd * 8)]);                                      \
      const short8 kh1 = *reinterpret_cast<const short8*>(                     \
          &sKh[b_][kr][swz(kr, 32 + qd * 8)]);                                 \
      const short8 kl0 = *reinterpret_cast<const short8*>(                     \
          &sKl[b_][kr][swz(kr, qd * 8)]);                                      \
      const short8 kl1 = *reinterpret_cast<const short8*>(                     \
          &sKl[b_][kr][swz(kr, 32 + qd * 8)]);                                 \
      _Pragma("unroll") for (int s = 0; s < 2; ++s) {                          \
        ACC[s][nt] = mfma16(kh0, bqh[s][0], z4);                               \
        ACC[s][nt] = mfma16(kh1, bqh[s][1], ACC[s][nt]);                       \
        ACC[s][nt] = mfma16(kh0, bql[s][0], ACC[s][nt]);                       \
        ACC[s][nt] = mfma16(kh1, bql[s][1], ACC[s][nt]);                       \
        ACC[s][nt] = mfma16(kl0, bqh[s][0], ACC[s][nt]);                       \
        ACC[s][nt] = mfma16(kl1, bqh[s][1], ACC[s][nt]);                       \
      }                                                                        \
    }                                                                          \
  } while (0)

  // softmax(ACC) with defer-max + PV from buffer bc_.
#define SMPV_PHASE(ACC, bc_)                                                   \
  do {                                                                         \
    uint pkd[2][4][2];                                                         \
    _Pragma("unroll") for (int s = 0; s < 2; ++s) {                            \
      float tmax = fmaxf(fmaxf(ACC[s][0][0], ACC[s][0][1]), ACC[s][0][2]);     \
      tmax = fmaxf(fmaxf(tmax, ACC[s][0][3]), ACC[s][1][0]);                   \
      tmax = fmaxf(fmaxf(tmax, ACC[s][1][1]), ACC[s][1][2]);                   \
      tmax = fmaxf(fmaxf(tmax, ACC[s][1][3]), ACC[s][2][0]);                   \
      tmax = fmaxf(fmaxf(tmax, ACC[s][2][1]), ACC[s][2][2]);                   \
      tmax = fmaxf(fmaxf(tmax, ACC[s][2][3]), ACC[s][3][0]);                   \
      tmax = fmaxf(fmaxf(tmax, ACC[s][3][1]), ACC[s][3][2]);                   \
      tmax = fmaxf(tmax, ACC[s][3][3]);                                        \
      tmax = fmaxf(tmax, __shfl_xor(tmax, 16));                                \
      tmax = fmaxf(tmax, __shfl_xor(tmax, 32));                                \
      if (tmax > m_run[s] + 8.f) {      /* T13: rescale only on real growth */ \
        const float mnew  = fmaxf(m_run[s], tmax);                             \
        const float alpha = exp2f(m_run[s] - mnew);                            \
        m_run[s] = mnew;                                                       \
        _Pragma("unroll") for (int nt = 0; nt < 4; ++nt)                       \
          _Pragma("unroll") for (int i = 0; i < 4; ++i)                        \
            accO[s][nt][i] *= alpha;                                           \
        accL[s][0] *= alpha;                                                   \
      }                                                                        \
      const float mr = m_run[s];                                               \
      _Pragma("unroll") for (int nt = 0; nt < 4; ++nt) {                       \
        pkd[s][nt][0] = pack_bf16(exp2f(ACC[s][nt][0] - mr),                   \
                                  exp2f(ACC[s][nt][1] - mr));                  \
        pkd[s][nt][1] = pack_bf16(exp2f(ACC[s][nt][2] - mr),                   \
                                  exp2f(ACC[s][nt][3] - mr));                  \
      }                                                                        \
    }                                                                          \
    _Pragma("unroll") for (int kt2 = 0; kt2 < 2; ++kt2) {                      \
      short8 pfrag[2];                                                         \
      _Pragma("unroll") for (int s = 0; s < 2; ++s) {                          \
        uint4 du;                                                              \
        du.x = pkd[s][kt2][0];                                                 \
        du.y = pkd[s][kt2][1];                                                 \
        du.z = pkd[s][kt2 + 2][0];                                             \
        du.w = pkd[s][kt2 + 2][1];                                             \
        pfrag[s] = *reinterpret_cast<short8*>(&du);                            \
      }                                                                        \
      _Pragma("unroll") for (int nt2 = 0; nt2 < 4; ++nt2) {                    \
        const int vr = nt2 * 16 + ln;                                          \
        const short8 vA = *reinterpret_cast<const short8*>(                    \
            &sVt[bc_][vr][swz(vr, kt2 * 32 + qd * 8)]);                        \
        accO[0][nt2] = mfma16(vA, pfrag[0], accO[0][nt2]);                     \
        accO[1][nt2] = mfma16(vA, pfrag[1], accO[1][nt2]);                     \
      }                                                                        \
      accL[0] = mfma16(afr1, pfrag[0], accL[0]);                               \
      accL[1] = mfma16(afr1, pfrag[1], accL[1]);                               \
    }                                                                          \
  } while (0)

  // ----- prologue: stage tiles 0,1; hold tile 2 in regs; QK(0) -----
  LOAD_TILES(k0base);
  STORE_TILES(0);
  LOAD_TILES(k0base + BK);
  STORE_TILES(1);
  LOAD_TILES(k0base + 2 * BK);
  bar_lgkm();
  QK_PHASE(accSA, 0);

  // ----- 16 fully-unrolled bodies, compile-time buffer indices -----
#define BODY(t_, AC, AN)                                                       \
  do {                                                                         \
    if ((t_) <= NIT - 3) STORE_TILES(((t_) + 2) % 3);                          \
    if ((t_) <= NIT - 4) LOAD_TILES(k0base + ((t_) + 3) * BK);                 \
    if ((t_) <= NIT - 2) QK_PHASE(AN, ((t_) + 1) % 3);                         \
    SMPV_PHASE(AC, (t_) % 3);                                                  \
    if ((t_) <= NIT - 2) bar_lgkm();                                           \
  } while (0)

  BODY(0,  accSA, accSB);
  BODY(1,  accSB, accSA);
  BODY(2,  accSA, accSB);
  BODY(3,  accSB, accSA);
  BODY(4,  accSA, accSB);
  BODY(5,  accSB, accSA);
  BODY(6,  accSA, accSB);
  BODY(7,  accSB, accSA);
  BODY(8,  accSA, accSB);
  BODY(9,  accSB, accSA);
  BODY(10, accSA, accSB);
  BODY(11, accSB, accSA);
  BODY(12, accSA, accSB);
  BODY(13, accSB, accSA);
  BODY(14, accSA, accSB);
  BODY(15, accSB, accSA);
#undef BODY
#undef QK_PHASE
#undef SMPV_PHASE
#undef LOAD_TILES
#undef STORE_TILES

#pragma unroll
  for (int s = 0; s < 2; ++s) {
    const int qrow = qrow0 + s * 16 + ln;
    ushort* Ob = Opart + ((size_t)sg * SEQ + qrow) * DH;
#pragma unroll
    for (int nt = 0; nt < 4; ++nt) {
      ushort op[4] __attribute__((aligned(8)));
#pragma unroll
      for (int r = 0; r < 4; ++r) op[r] = bf16_of(accO[s][nt][r]);
      *reinterpret_cast<us4*>(Ob + nt * 16 + qd * 4) =
          *reinterpret_cast<us4*>(op);
    }
    if (qd == 0) {
      Mpart[(size_t)sg * SEQ + qrow] = m_run[s];
      Lpart[(size_t)sg * SEQ + qrow] = accL[s][0];
    }
  }
}

// ---------------------------------------------------------------------------
// Phase 3 (merge logic, UNCHANGED; one item per thread at 512 blocks).
// ---------------------------------------------------------------------------
static __device__ void merge_phase(
    const ushort* __restrict__ Opart, const float* __restrict__ Mpart,
    const float* __restrict__ Lpart, float* __restrict__ out) {
  const int idx = blockIdx.x * 256 + threadIdx.x;   // 0 .. SEQ*16
  const int row = idx >> 4;
  const int c4  = (idx & 15) * 4;

  float m[SG];
  float M = -INFINITY;
#pragma unroll
  for (int i = 0; i < SG; ++i) {
    m[i] = Mpart[(size_t)i * SEQ + row];
    M = fmaxf(M, m[i]);
  }
  float L = 0.f;
  float a0 = 0.f, a1 = 0.f, a2 = 0.f, a3 = 0.f;
#pragma unroll
  for (int i = 0; i < SG; ++i) {
    const float w = exp2f(m[i] - M);
    L += w * Lpart[(size_t)i * SEQ + row];
    const us4 o = *reinterpret_cast<const us4*>(
        Opart + ((size_t)i * SEQ + row) * DH + c4);
    a0 += w * f_of_bf16(o[0]);
    a1 += w * f_of_bf16(o[1]);
    a2 += w * f_of_bf16(o[2]);
    a3 += w * f_of_bf16(o[3]);
  }
  const float rL = 1.0f / L;
  float4 res = make_float4(a0 * rL, a1 * rL, a2 * rL, a3 * rL);
  *reinterpret_cast<float4*>(out + (size_t)row * DH + c4) = res;
}

// ---------------------------------------------------------------------------
// R17: ONE cooperative dispatch.  All three phases already map to exactly
// 512 blocks x 256 threads; LDS 73728 B -> 2 blocks/CU -> 512 co-resident
// blocks = cooperative capacity exactly.  grid.sync() (+ __threadfence for
// device-scope visibility across non-coherent XCD L2s) replaces the two
// inter-kernel boundaries, eliminating 2x dispatch overhead + gaps
// (R10 datum: ~12-14 us per dispatch incl. overhead).
// ---------------------------------------------------------------------------
__global__ __launch_bounds__(256, 2) void fused_kernel(
    const float* __restrict__ x,  const float* __restrict__ Wq,
    const float* __restrict__ Wk, const float* __restrict__ Wv,
    ushort* __restrict__ Qh, ushort* __restrict__ Ql,
    ushort* __restrict__ Kh, ushort* __restrict__ Kl,
    ushort* __restrict__ Vt, ushort* __restrict__ Op,
    float* __restrict__ Mp, float* __restrict__ Lp,
    float* __restrict__ out) {
  __shared__ __attribute__((aligned(16))) char smem[SMEM_BYTES];

  pgemm_phase(smem, x, Wq, Wk, Wv, Qh, Ql, Kh, Kl, Vt);
  __threadfence();
  cg::this_grid().sync();
  flash_phase(smem, Qh, Ql, Kh, Kl, Vt, Op, Mp, Lp);
  __threadfence();
  cg::this_grid().sync();
  merge_phase(Op, Mp, Lp, out);
}

// ---------------------------------------------------------------------------
// Fallback path (R16 behavior): three standalone kernels, same phase code.
// Used only if the cooperative launch is rejected (e.g. by graph capture).
// ---------------------------------------------------------------------------
__global__ __launch_bounds__(256, 2) void pgemm_kernel(
    const float* __restrict__ x,  const float* __restrict__ Wq,
    const float* __restrict__ Wk, const float* __restrict__ Wv,
    ushort* __restrict__ Qh, ushort* __restrict__ Ql,
    ushort* __restrict__ Kh, ushort* __restrict__ Kl,
    ushort* __restrict__ Vt) {
  __shared__ __attribute__((aligned(16))) char smem[16 * SXP * 4];
  pgemm_phase(smem, x, Wq, Wk, Wv, Qh, Ql, Kh, Kl, Vt);
}

__global__ __launch_bounds__(256, 2) void flash_kernel(
    const ushort* __restrict__ Qh, const ushort* __restrict__ Ql,
    const ushort* __restrict__ Kh, const ushort* __restrict__ Kl,
    const ushort* __restrict__ Vt,
    ushort* __restrict__ Opart, float* __restrict__ Mpart,
    float* __restrict__ Lpart) {
  __shared__ __attribute__((aligned(16))) char smem[SMEM_BYTES];
  flash_phase(smem, Qh, Ql, Kh, Kl, Vt, Opart, Mpart, Lpart);
}

__global__ __launch_bounds__(256) void merge_kernel(
    const ushort* __restrict__ Opart, const float* __restrict__ Mpart,
    const float* __restrict__ Lpart, float* __restrict__ out) {
  merge_phase(Opart, Mpart, Lpart, out);
}

// ---------------------------------------------------------------------------
extern "C" void kernel_launch(void* const* d_in, const int* in_sizes, int n_in,
                              void* d_out, int out_size, void* d_ws, size_t ws_size,
                              hipStream_t stream) {
  const float* x  = (const float*)d_in[0];
  const float* Wq = (const float*)d_in[1];
  const float* Wk = (const float*)d_in[2];
  const float* Wv = (const float*)d_in[3];
  float* out = (float*)d_out;

  // workspace layout — 14,155,776 B (SG=8 partials, as R12).
  const size_t S64 = (size_t)SEQ * DH;        // 524288
  ushort* Qh = (ushort*)d_ws;
  ushort* Ql = Qh + S64;
  ushort* Kh = Ql + S64;
  ushort* Kl = Kh + S64;
  ushort* Vt = Kl + S64;
  ushort* Op = Vt + S64;                      // [SG][SEQ][DH] bf16
  float*  Mp = (float*)(Op + (size_t)SG * S64);
  float*  Lp = Mp + (size_t)SG * SEQ;

  void* args[] = {(void*)&x,  (void*)&Wq, (void*)&Wk, (void*)&Wv,
                  (void*)&Qh, (void*)&Ql, (void*)&Kh, (void*)&Kl,
                  (void*)&Vt, (void*)&Op, (void*)&Mp, (void*)&Lp,
                  (void*)&out};
  const hipError_t e = hipLaunchCooperativeKernel(
      reinterpret_cast<void*>(fused_kernel), dim3(512), dim3(256), args, 0,
      stream);
  if (e != hipSuccess) {
    // Fallback: identical math as three plain dispatches (R16 behavior).
    pgemm_kernel<<<SEQ / 16, 256, 0, stream>>>(x, Wq, Wk, Wv, Qh, Ql, Kh, Kl, Vt);
    flash_kernel<<<(SEQ / 128) * SG, 256, 0, stream>>>(Qh, Ql, Kh, Kl, Vt, Op, Mp, Lp);
    merge_kernel<<<(SEQ * 16) / 256, 256, 0, stream>>>(Op, Mp, Lp, out);
  }
}

// Round 6
// 213.636 us; speedup vs baseline: 2.1560x; 2.1560x over previous
//
#include <hip/hip_runtime.h>
#include <hip/hip_bf16.h>
#include <math.h>

#define SEQ 8192
#define DIN 512
#define DH  64
#define SG  8                 // grid 512 = 2 blocks/CU exact (3-buffer LDS)
#define CHUNK (SEQ / SG)      // 1024 K-rows per flash block
#define BK  64                // K/V rows per iteration
#define NIT (CHUNK / BK)      // 16 iterations (compile-time)
#define LDK 64                // flash LDS row stride (bf16): 128B, XOR-swizzled
#define SXP 516               // padded fp32 x row stride (pgemm)

typedef float f32x4 __attribute__((ext_vector_type(4)));
typedef short short8 __attribute__((ext_vector_type(8)));
typedef ushort us4 __attribute__((ext_vector_type(4)));

// R18: fan-in merge counters, one per 128-row Q tile.  Module-scope device
// globals are zero-initialized at load; used MONOTONICALLY ((old&7)==7
// detects the 8th arrival of each graph replay), so no reset is ever
// needed and the workspace layout is untouched.
__device__ uint g_cnt[SEQ / 128];

static __device__ __forceinline__ ushort bf16_of(float v) {
  __hip_bfloat16 h = __float2bfloat16(v);
  return *reinterpret_cast<ushort*>(&h);
}
static __device__ __forceinline__ float f_of_bf16(ushort u) {
  __hip_bfloat16 h;
  *reinterpret_cast<ushort*>(&h) = u;
  return __bfloat162float(h);
}
static __device__ __forceinline__ f32x4 mfma16(short8 a, short8 b, f32x4 c) {
  return __builtin_amdgcn_mfma_f32_16x16x32_bf16(a, b, c, 0, 0, 0);
}
static __device__ __forceinline__ uint pack_bf16(float a, float b) {
  __hip_bfloat162 h2 = __float22bfloat162_rn(make_float2(a, b));
  return *reinterpret_cast<uint*>(&h2);
}
// K-row permutation (R12-proven): physical row p -> LDS slot, chosen so the
// S^T C-layout ownership coincides with the PV B-operand k-ownership,
// making the P^T fragment pure register renaming.
static __device__ __forceinline__ int slot_of(int p) {
  return ((((p >> 2) & 1) * 2 + (p >> 5)) << 4) | (((p >> 3) & 3) << 2) | (p & 3);
}
// R13-proven XOR chunk swizzle (bank conflicts 3.1M -> 0, measured).
static __device__ __forceinline__ int swz(int row, int col) {
  return col ^ ((row & 7) << 3);
}
// R16-proven lgkm-only barrier (global prefetch loads stay in flight).
static __device__ __forceinline__ void bar_lgkm() {
  asm volatile("s_waitcnt lgkmcnt(0)" ::: "memory");
  __builtin_amdgcn_s_barrier();
}

// ---------------------------------------------------------------------------
// Kernel 1 (pgemm v4, UNCHANGED).
// ---------------------------------------------------------------------------
__global__ __launch_bounds__(256, 2) void pgemm_kernel(
    const float* __restrict__ x,  const float* __restrict__ Wq,
    const float* __restrict__ Wk, const float* __restrict__ Wv,
    ushort* __restrict__ Qh, ushort* __restrict__ Ql,
    ushort* __restrict__ Kh, ushort* __restrict__ Kl,
    ushort* __restrict__ Vt) {
  __shared__ float sx[16][SXP];               // 33 KB; reused as merge buf
  float* mb = &sx[0][0];

  const int tid = threadIdx.x;
  const int wv = tid >> 6, lane = tid & 63;
  const int ln = lane & 15, qd = lane >> 4;
  const int rb = blockIdx.x * 16;

  {
    const float4* xg = reinterpret_cast<const float4*>(x + (size_t)rb * DIN);
#pragma unroll
    for (int j = 0; j < 8; ++j) {
      const int idx = tid + 256 * j;
      const int row = idx >> 7;
      const int col = (idx & 127) * 4;
      *reinterpret_cast<float4*>(&sx[row][col]) = xg[idx];
    }
  }
  __syncthreads();

  f32x4 acc[3][4];
#pragma unroll
  for (int m = 0; m < 3; ++m)
#pragma unroll
    for (int nt = 0; nt < 4; ++nt)
#pragma unroll
      for (int i = 0; i < 4; ++i) acc[m][nt][i] = 0.f;

  const int kb = wv * 128;
  const int wbase = (kb + qd * 8) * 64 + ln;

  float wf[2][32];
#define LDW(kt_, m_, buf_)                                                     \
  do {                                                                         \
    const float* W_ = ((m_) == 0) ? Wq : (((m_) == 1) ? Wk : Wv);              \
    const int o_ = wbase + (kt_) * 32 * 64;                                    \
    _Pragma("unroll") for (int nt = 0; nt < 4; ++nt)                           \
      _Pragma("unroll") for (int j = 0; j < 8; ++j)                            \
        wf[buf_][nt * 8 + j] = W_[o_ + j * 64 + nt * 16];                      \
  } while (0)

  LDW(0, 0, 0);
#pragma unroll
  for (int kt = 0; kt < 4; ++kt) {
    const int k0 = kb + kt * 32;
    float xs[8];
    *reinterpret_cast<float4*>(xs) =
        *reinterpret_cast<const float4*>(&sx[ln][k0 + qd * 8]);
    *reinterpret_cast<float4*>(xs + 4) =
        *reinterpret_cast<const float4*>(&sx[ln][k0 + qd * 8 + 4]);
    ushort ah[8] __attribute__((aligned(16)));
    ushort al[8] __attribute__((aligned(16)));
#pragma unroll
    for (int j = 0; j < 8; ++j) {
      const ushort h = bf16_of(xs[j]);
      ah[j] = h;
      al[j] = bf16_of(xs[j] - f_of_bf16(h));
    }
    const short8 Ah = *reinterpret_cast<short8*>(ah);
    const short8 Al = *reinterpret_cast<short8*>(al);
#pragma unroll
    for (int m = 0; m < 3; ++m) {
      const int g = kt * 3 + m;               // compile-time (unrolled)
      const int buf = g & 1;
      if (g < 11) {
        const int gn = g + 1;
        LDW(gn / 3, gn % 3, buf ^ 1);         // prefetch next group's W fp32
      }
      const float scale = (m == 0) ? 0.125f * 1.44269504088896f : 1.0f;
#pragma unroll
      for (int nt = 0; nt < 4; ++nt) {
        ushort bh8[8] __attribute__((aligned(16)));
        ushort bl8[8] __attribute__((aligned(16)));
#pragma unroll
        for (int j = 0; j < 8; ++j) {
          const float v = wf[buf][nt * 8 + j] * scale;
          const ushort h = bf16_of(v);
          bh8[j] = h;
          bl8[j] = bf16_of(v - f_of_bf16(h));
        }
        const short8 bh = *reinterpret_cast<short8*>(bh8);
        const short8 bl = *reinterpret_cast<short8*>(bl8);
        acc[m][nt] = mfma16(Ah, bh, acc[m][nt]);
        acc[m][nt] = mfma16(Ah, bl, acc[m][nt]);
        acc[m][nt] = mfma16(Al, bh, acc[m][nt]);
      }
    }
  }
#undef LDW

  const int eidx = (qd * 4) * 64 + ln;
  __syncthreads();
  if (wv >= 2) {
    float* b = mb + (size_t)(wv - 2) * 3072;
#pragma unroll
    for (int m = 0; m < 3; ++m)
#pragma unroll
      for (int nt = 0; nt < 4; ++nt)
#pragma unroll
        for (int r = 0; r < 4; ++r)
          b[m * 1024 + eidx + r * 64 + nt * 16] = acc[m][nt][r];
  }
  __syncthreads();
  if (wv < 2) {
    const float* b = mb + (size_t)wv * 3072;
#pragma unroll
    for (int m = 0; m < 3; ++m)
#pragma unroll
      for (int nt = 0; nt < 4; ++nt)
#pragma unroll
        for (int r = 0; r < 4; ++r)
          acc[m][nt][r] += b[m * 1024 + eidx + r * 64 + nt * 16];
  }
  __syncthreads();
  if (wv == 1) {
#pragma unroll
    for (int m = 0; m < 3; ++m)
#pragma unroll
      for (int nt = 0; nt < 4; ++nt)
#pragma unroll
        for (int r = 0; r < 4; ++r)
          mb[m * 1024 + eidx + r * 64 + nt * 16] = acc[m][nt][r];
  }
  __syncthreads();
  if (wv == 0) {
#pragma unroll
    for (int m = 0; m < 3; ++m)
#pragma unroll
      for (int nt = 0; nt < 4; ++nt)
#pragma unroll
        for (int r = 0; r < 4; ++r)
          acc[m][nt][r] += mb[m * 1024 + eidx + r * 64 + nt * 16];

#pragma unroll
    for (int m = 0; m < 2; ++m) {
      ushort* H = (m == 0) ? Qh : Kh;
      ushort* L = (m == 0) ? Ql : Kl;
#pragma unroll
      for (int nt = 0; nt < 4; ++nt)
#pragma unroll
        for (int r = 0; r < 4; ++r) {
          const float v = acc[m][nt][r];
          const int row = rb + qd * 4 + r;
          const int col = nt * 16 + ln;
          const ushort h = bf16_of(v);
          H[(size_t)row * DH + col] = h;
          L[(size_t)row * DH + col] = bf16_of(v - f_of_bf16(h));
        }
    }
#pragma unroll
    for (int nt = 0; nt < 4; ++nt) {
      ushort vp[4] __attribute__((aligned(8)));
#pragma unroll
      for (int r = 0; r < 4; ++r) vp[r] = bf16_of(acc[2][nt][r]);
      *reinterpret_cast<us4*>(Vt + (size_t)(nt * 16 + ln) * SEQ + rb + qd * 4) =
          *reinterpret_cast<us4*>(vp);
    }
  }
}

// ---------------------------------------------------------------------------
// Kernel 2 (flash v10 = R16 flash v9 + R18 fan-in merge).  Main loop and
// numerics byte-identical to R16.  Epilogue: after partial stores, each
// block does threadfence -> syncthreads -> tid0 atomicAdd(g_cnt[qt]); the
// 8th (last) arriving block of each qt performs that qt's 128-row merge
// inline (canonical threadFenceReduction fan-in: device-scope atomics +
// fences per Guideline 12/16; NO spin, NO co-residency assumption, normal
// launch = normal caching, none of R17's coherent-mode poison).
// ---------------------------------------------------------------------------
__global__ __launch_bounds__(256, 2) void flash_kernel(
    const ushort* __restrict__ Qh, const ushort* __restrict__ Ql,
    const ushort* __restrict__ Kh, const ushort* __restrict__ Kl,
    const ushort* __restrict__ Vt,
    ushort* __restrict__ Opart, float* __restrict__ Mpart,
    float* __restrict__ Lpart, float* __restrict__ out) {
  __shared__ __attribute__((aligned(16))) ushort sKh[3][BK][LDK];  // 24 KB
  __shared__ __attribute__((aligned(16))) ushort sKl[3][BK][LDK];  // 24 KB
  __shared__ __attribute__((aligned(16))) ushort sVt[3][DH][LDK];  // 24 KB
  __shared__ int sLast;

  const int tid  = threadIdx.x;
  const int wv   = tid >> 6;
  const int lane = tid & 63;
  const int ln   = lane & 15;
  const int qd   = lane >> 4;
  const int bid  = blockIdx.x;
  const int sg   = bid & (SG - 1);
  const int qt   = bid >> 3;            // 0..63 (128-row Q tiles)
  const int qrow0  = qt * 128 + wv * 32;   // set s adds s*16
  const int k0base = sg * CHUNK;

  const int r0 = tid >> 3, g0 = (tid & 7) * 8;
  const int r1 = r0 + 32,  g1 = g0;
  const int sr0 = slot_of(r0), sr1 = slot_of(r1);   // permuted K slots

  const ushort one_u = (ln == 0) ? (ushort)0x3F80 : (ushort)0;
  short8 afr1;
#pragma unroll
  for (int j = 0; j < 8; ++j) afr1[j] = (short)one_u;

  short8 bqh[2][2], bql[2][2];
#pragma unroll
  for (int s = 0; s < 2; ++s)
#pragma unroll
    for (int kt = 0; kt < 2; ++kt) {
      bqh[s][kt] = *reinterpret_cast<const short8*>(
          Qh + (size_t)(qrow0 + s * 16 + ln) * DH + kt * 32 + qd * 8);
      bql[s][kt] = *reinterpret_cast<const short8*>(
          Ql + (size_t)(qrow0 + s * 16 + ln) * DH + kt * 32 + qd * 8);
    }

  f32x4 accO[2][4], accL[2];
  float m_run[2] = {-INFINITY, -INFINITY};
#pragma unroll
  for (int s = 0; s < 2; ++s) {
#pragma unroll
    for (int nt = 0; nt < 4; ++nt)
#pragma unroll
      for (int i = 0; i < 4; ++i) accO[s][nt][i] = 0.f;
#pragma unroll
    for (int i = 0; i < 4; ++i) accL[s][i] = 0.f;
  }
  const f32x4 z4 = {0.f, 0.f, 0.f, 0.f};   // persistent zero C-operand

  f32x4 accSA[2][4], accSB[2][4];          // 2-deep S pipeline

  uint4 pk0, pk1, pl0, pl1, pv0, pv1;
#define LOAD_TILES(k0_)                                                        \
  do {                                                                         \
    pk0 = *reinterpret_cast<const uint4*>(Kh + (size_t)((k0_) + r0) * DH + g0);\
    pk1 = *reinterpret_cast<const uint4*>(Kh + (size_t)((k0_) + r1) * DH + g1);\
    pl0 = *reinterpret_cast<const uint4*>(Kl + (size_t)((k0_) + r0) * DH + g0);\
    pl1 = *reinterpret_cast<const uint4*>(Kl + (size_t)((k0_) + r1) * DH + g1);\
    pv0 = *reinterpret_cast<const uint4*>(Vt + (size_t)r0 * SEQ + (k0_) + g0); \
    pv1 = *reinterpret_cast<const uint4*>(Vt + (size_t)r1 * SEQ + (k0_) + g1); \
  } while (0)
#define STORE_TILES(b_)                                                        \
  do {                                                                         \
    *reinterpret_cast<uint4*>(&sKh[b_][sr0][swz(sr0, g0)]) = pk0;              \
    *reinterpret_cast<uint4*>(&sKh[b_][sr1][swz(sr1, g1)]) = pk1;              \
    *reinterpret_cast<uint4*>(&sKl[b_][sr0][swz(sr0, g0)]) = pl0;              \
    *reinterpret_cast<uint4*>(&sKl[b_][sr1][swz(sr1, g1)]) = pl1;              \
    *reinterpret_cast<uint4*>(&sVt[b_][r0][swz(r0, g0)])   = pv0;              \
    *reinterpret_cast<uint4*>(&sVt[b_][r1][swz(r1, g1)])   = pv1;              \
  } while (0)

  // QK^T of one tile from buffer b_ into ACC (hi*hi + hi*lo + lo*hi).
#define QK_PHASE(ACC, b_)                                                      \
  do {                                                                         \
    _Pragma("unroll") for (int nt = 0; nt < 4; ++nt) {                         \
      const int kr = nt * 16 + ln;                                             \
      const short8 kh0 = *reinterpret_cast<const short8*>(                     \
          &sKh[b_][kr][swz(kr, qd * 8)]);                                      \
      const short8 kh1 = *reinterpret_cast<const short8*>(                     \
          &sKh[b_][kr][swz(kr, 32 + qd * 8)]);                                 \
      const short8 kl0 = *reinterpret_cast<const short8*>(                     \
          &sKl[b_][kr][swz(kr, qd * 8)]);                                      \
      const short8 kl1 = *reinterpret_cast<const short8*>(                     \
          &sKl[b_][kr][swz(kr, 32 + qd * 8)]);                                 \
      _Pragma("unroll") for (int s = 0; s < 2; ++s) {                          \
        ACC[s][nt] = mfma16(kh0, bqh[s][0], z4);                               \
        ACC[s][nt] = mfma16(kh1, bqh[s][1], ACC[s][nt]);                       \
        ACC[s][nt] = mfma16(kh0, bql[s][0], ACC[s][nt]);                       \
        ACC[s][nt] = mfma16(kh1, bql[s][1], ACC[s][nt]);                       \
        ACC[s][nt] = mfma16(kl0, bqh[s][0], ACC[s][nt]);                       \
        ACC[s][nt] = mfma16(kl1, bqh[s][1], ACC[s][nt]);                       \
      }                                                                        \
    }                                                                          \
  } while (0)

  // softmax(ACC) with defer-max + PV from buffer bc_.
#define SMPV_PHASE(ACC, bc_)                                                   \
  do {                                                                         \
    uint pkd[2][4][2];                                                         \
    _Pragma("unroll") for (int s = 0; s < 2; ++s) {                            \
      float tmax = fmaxf(fmaxf(ACC[s][0][0], ACC[s][0][1]), ACC[s][0][2]);     \
      tmax = fmaxf(fmaxf(tmax, ACC[s][0][3]), ACC[s][1][0]);                   \
      tmax = fmaxf(fmaxf(tmax, ACC[s][1][1]), ACC[s][1][2]);                   \
      tmax = fmaxf(fmaxf(tmax, ACC[s][1][3]), ACC[s][2][0]);                   \
      tmax = fmaxf(fmaxf(tmax, ACC[s][2][1]), ACC[s][2][2]);                   \
      tmax = fmaxf(fmaxf(tmax, ACC[s][2][3]), ACC[s][3][0]);                   \
      tmax = fmaxf(fmaxf(tmax, ACC[s][3][1]), ACC[s][3][2]);                   \
      tmax = fmaxf(tmax, ACC[s][3][3]);                                        \
      tmax = fmaxf(tmax, __shfl_xor(tmax, 16));                                \
      tmax = fmaxf(tmax, __shfl_xor(tmax, 32));                                \
      if (tmax > m_run[s] + 8.f) {      /* T13: rescale only on real growth */ \
        const float mnew  = fmaxf(m_run[s], tmax);                             \
        const float alpha = exp2f(m_run[s] - mnew);                            \
        m_run[s] = mnew;                                                       \
        _Pragma("unroll") for (int nt = 0; nt < 4; ++nt)                       \
          _Pragma("unroll") for (int i = 0; i < 4; ++i)                        \
            accO[s][nt][i] *= alpha;                                           \
        accL[s][0] *= alpha;                                                   \
      }                                                                        \
      const float mr = m_run[s];                                               \
      _Pragma("unroll") for (int nt = 0; nt < 4; ++nt) {                       \
        pkd[s][nt][0] = pack_bf16(exp2f(ACC[s][nt][0] - mr),                   \
                                  exp2f(ACC[s][nt][1] - mr));                  \
        pkd[s][nt][1] = pack_bf16(exp2f(ACC[s][nt][2] - mr),                   \
                                  exp2f(ACC[s][nt][3] - mr));                  \
      }                                                                        \
    }                                                                          \
    _Pragma("unroll") for (int kt2 = 0; kt2 < 2; ++kt2) {                      \
      short8 pfrag[2];                                                         \
      _Pragma("unroll") for (int s = 0; s < 2; ++s) {                          \
        uint4 du;                                                              \
        du.x = pkd[s][kt2][0];                                                 \
        du.y = pkd[s][kt2][1];                                                 \
        du.z = pkd[s][kt2 + 2][0];                                             \
        du.w = pkd[s][kt2 + 2][1];                                             \
        pfrag[s] = *reinterpret_cast<short8*>(&du);                            \
      }                                                                        \
      _Pragma("unroll") for (int nt2 = 0; nt2 < 4; ++nt2) {                    \
        const int vr = nt2 * 16 + ln;                                          \
        const short8 vA = *reinterpret_cast<const short8*>(                    \
            &sVt[bc_][vr][swz(vr, kt2 * 32 + qd * 8)]);                        \
        accO[0][nt2] = mfma16(vA, pfrag[0], accO[0][nt2]);                     \
        accO[1][nt2] = mfma16(vA, pfrag[1], accO[1][nt2]);                     \
      }                                                                        \
      accL[0] = mfma16(afr1, pfrag[0], accL[0]);                               \
      accL[1] = mfma16(afr1, pfrag[1], accL[1]);                               \
    }                                                                          \
  } while (0)

  // ----- prologue: stage tiles 0,1; hold tile 2 in regs; QK(0) -----
  LOAD_TILES(k0base);
  STORE_TILES(0);
  LOAD_TILES(k0base + BK);
  STORE_TILES(1);
  LOAD_TILES(k0base + 2 * BK);
  bar_lgkm();
  QK_PHASE(accSA, 0);

  // ----- 16 fully-unrolled bodies, compile-time buffer indices -----
#define BODY(t_, AC, AN)                                                       \
  do {                                                                         \
    if ((t_) <= NIT - 3) STORE_TILES(((t_) + 2) % 3);                          \
    if ((t_) <= NIT - 4) LOAD_TILES(k0base + ((t_) + 3) * BK);                 \
    if ((t_) <= NIT - 2) QK_PHASE(AN, ((t_) + 1) % 3);                         \
    SMPV_PHASE(AC, (t_) % 3);                                                  \
    if ((t_) <= NIT - 2) bar_lgkm();                                           \
  } while (0)

  BODY(0,  accSA, accSB);
  BODY(1,  accSB, accSA);
  BODY(2,  accSA, accSB);
  BODY(3,  accSB, accSA);
  BODY(4,  accSA, accSB);
  BODY(5,  accSB, accSA);
  BODY(6,  accSA, accSB);
  BODY(7,  accSB, accSA);
  BODY(8,  accSA, accSB);
  BODY(9,  accSB, accSA);
  BODY(10, accSA, accSB);
  BODY(11, accSB, accSA);
  BODY(12, accSA, accSB);
  BODY(13, accSB, accSA);
  BODY(14, accSA, accSB);
  BODY(15, accSB, accSA);
#undef BODY
#undef QK_PHASE
#undef SMPV_PHASE
#undef LOAD_TILES
#undef STORE_TILES

#pragma unroll
  for (int s = 0; s < 2; ++s) {
    const int qrow = qrow0 + s * 16 + ln;
    ushort* Ob = Opart + ((size_t)sg * SEQ + qrow) * DH;
#pragma unroll
    for (int nt = 0; nt < 4; ++nt) {
      ushort op[4] __attribute__((aligned(8)));
#pragma unroll
      for (int r = 0; r < 4; ++r) op[r] = bf16_of(accO[s][nt][r]);
      *reinterpret_cast<us4*>(Ob + nt * 16 + qd * 4) =
          *reinterpret_cast<us4*>(op);
    }
    if (qd == 0) {
      Mpart[(size_t)sg * SEQ + qrow] = m_run[s];
      Lpart[(size_t)sg * SEQ + qrow] = accL[s][0];
    }
  }

  // ----- R18 fan-in merge: last-arriving block of this qt merges it -----
  __threadfence();                       // release this block's partials
  __syncthreads();                       // all 256 threads' stores fenced
  if (tid == 0) {
    const uint old = atomicAdd(&g_cnt[qt], 1u);
    sLast = ((old & (SG - 1)) == (SG - 1)) ? 1 : 0;
  }
  __syncthreads();
  if (sLast) {
    __threadfence();                     // acquire other blocks' partials
    for (int i = tid; i < 128 * 16; i += 256) {
      const int row = qt * 128 + (i >> 4);
      const int c4  = (i & 15) * 4;
      float mv[SG];
      float M = -INFINITY;
#pragma unroll
      for (int p = 0; p < SG; ++p) {
        mv[p] = Mpart[(size_t)p * SEQ + row];
        M = fmaxf(M, mv[p]);
      }
      float L = 0.f;
      float a0 = 0.f, a1 = 0.f, a2 = 0.f, a3 = 0.f;
#pragma unroll
      for (int p = 0; p < SG; ++p) {
        const float w = exp2f(mv[p] - M);
        L += w * Lpart[(size_t)p * SEQ + row];
        const us4 o = *reinterpret_cast<const us4*>(
            Opart + ((size_t)p * SEQ + row) * DH + c4);
        a0 += w * f_of_bf16(o[0]);
        a1 += w * f_of_bf16(o[1]);
        a2 += w * f_of_bf16(o[2]);
        a3 += w * f_of_bf16(o[3]);
      }
      const float rL = 1.0f / L;
      float4 res = make_float4(a0 * rL, a1 * rL, a2 * rL, a3 * rL);
      *reinterpret_cast<float4*>(out + (size_t)row * DH + c4) = res;
    }
  }
}

// ---------------------------------------------------------------------------
extern "C" void kernel_launch(void* const* d_in, const int* in_sizes, int n_in,
                              void* d_out, int out_size, void* d_ws, size_t ws_size,
                              hipStream_t stream) {
  const float* x  = (const float*)d_in[0];
  const float* Wq = (const float*)d_in[1];
  const float* Wk = (const float*)d_in[2];
  const float* Wv = (const float*)d_in[3];
  float* out = (float*)d_out;

  // workspace layout — 14,155,776 B (SG=8 partials, unchanged from R12/R16).
  const size_t S64 = (size_t)SEQ * DH;        // 524288
  ushort* Qh = (ushort*)d_ws;
  ushort* Ql = Qh + S64;
  ushort* Kh = Ql + S64;
  ushort* Kl = Kh + S64;
  ushort* Vt = Kl + S64;
  ushort* Op = Vt + S64;                      // [SG][SEQ][DH] bf16
  float*  Mp = (float*)(Op + (size_t)SG * S64);
  float*  Lp = Mp + (size_t)SG * SEQ;

  pgemm_kernel<<<SEQ / 16, 256, 0, stream>>>(x, Wq, Wk, Wv, Qh, Ql, Kh, Kl, Vt);
  flash_kernel<<<(SEQ / 128) * SG, 256, 0, stream>>>(Qh, Ql, Kh, Kl, Vt, Op, Mp,
                                                     Lp, out);
}

// Round 8
// 122.911 us; speedup vs baseline: 3.7474x; 1.7381x over previous
//
#include <hip/hip_runtime.h>
#include <hip/hip_bf16.h>
#include <math.h>

#define SEQ 8192
#define DIN 512
#define DH  64
#define SG  8                 // grid 512 = 2 blocks/CU exact
#define CHUNK (SEQ / SG)      // 1024 K-rows per flash block
#define BK  64                // K/V rows per iteration
#define NIT (CHUNK / BK)      // 16 iterations (compile-time)
#define LDK 64                // flash LDS row stride: 128B, XOR-swizzled
#define SXP 516               // padded fp32 x row stride (pgemm)

typedef float f32x4 __attribute__((ext_vector_type(4)));
typedef short short8 __attribute__((ext_vector_type(8)));
typedef ushort us4 __attribute__((ext_vector_type(4)));
typedef _Float16 half8 __attribute__((ext_vector_type(8)));
typedef __fp16 fp16x2 __attribute__((ext_vector_type(2)));   // cvt_pkrtz ret type

// ----- bf16 helpers (pgemm internal hi-lo GEMM arithmetic, unchanged) -----
static __device__ __forceinline__ ushort bf16_of(float v) {
  __hip_bfloat16 h = __float2bfloat16(v);
  return *reinterpret_cast<ushort*>(&h);
}
static __device__ __forceinline__ float f_of_bf16(ushort u) {
  __hip_bfloat16 h;
  *reinterpret_cast<ushort*>(&h) = u;
  return __bfloat162float(h);
}
static __device__ __forceinline__ f32x4 mfma16(short8 a, short8 b, f32x4 c) {
  return __builtin_amdgcn_mfma_f32_16x16x32_bf16(a, b, c, 0, 0, 0);
}
// ----- R19 fp16 helpers -----
static __device__ __forceinline__ ushort f16b(float v) {       // RN convert
  _Float16 h = (_Float16)v;
  return *reinterpret_cast<ushort*>(&h);
}
static __device__ __forceinline__ float f_of_f16(ushort u) {
  _Float16 h = *reinterpret_cast<_Float16*>(&u);
  return (float)h;
}
static __device__ __forceinline__ f32x4 mfma16f(short8 a, short8 b, f32x4 c) {
  return __builtin_amdgcn_mfma_f32_16x16x32_f16(
      __builtin_bit_cast(half8, a), __builtin_bit_cast(half8, b), c, 0, 0, 0);
}
static __device__ __forceinline__ uint pack_f16(float a, float b) {
  // single-instruction packed convert (RTZ; P in [0,256] -> <=1ulp, fine)
  fp16x2 h = __builtin_amdgcn_cvt_pkrtz(a, b);
  return __builtin_bit_cast(uint, h);
}
// K-row permutation (R12-proven): S^T C-layout ownership == PV B-operand
// k-ownership -> P^T fragment is pure register renaming.
static __device__ __forceinline__ int slot_of(int p) {
  return ((((p >> 2) & 1) * 2 + (p >> 5)) << 4) | (((p >> 3) & 3) << 2) | (p & 3);
}
// R13-proven XOR chunk swizzle (bank conflicts 3.1M -> 0, measured).
static __device__ __forceinline__ int swz(int row, int col) {
  return col ^ ((row & 7) << 3);
}
// R16-proven lgkm-only barrier (global prefetch loads stay in flight).
static __device__ __forceinline__ void bar_lgkm() {
  asm volatile("s_waitcnt lgkmcnt(0)" ::: "memory");
  __builtin_amdgcn_s_barrier();
}

// ---------------------------------------------------------------------------
// Kernel 1 (pgemm v5): internal x@W hi-lo bf16 GEMM unchanged (fp32 acc);
// OUTPUT ENCODING now fp16: Q -> Qh+Ql (fp16 hi/lo, Q exact to 2^-22),
// K -> Kh only (fp16; the dropped Kl*Q term is the 0.04-exp2-unit error
// budget), V^T -> fp16.  Kl path deleted.
// ---------------------------------------------------------------------------
__global__ __launch_bounds__(256, 2) void pgemm_kernel(
    const float* __restrict__ x,  const float* __restrict__ Wq,
    const float* __restrict__ Wk, const float* __restrict__ Wv,
    ushort* __restrict__ Qh, ushort* __restrict__ Ql,
    ushort* __restrict__ Kh, ushort* __restrict__ Vt) {
  __shared__ float sx[16][SXP];               // 33 KB; reused as merge buf
  float* mb = &sx[0][0];

  const int tid = threadIdx.x;
  const int wv = tid >> 6, lane = tid & 63;
  const int ln = lane & 15, qd = lane >> 4;
  const int rb = blockIdx.x * 16;

  {
    const float4* xg = reinterpret_cast<const float4*>(x + (size_t)rb * DIN);
#pragma unroll
    for (int j = 0; j < 8; ++j) {
      const int idx = tid + 256 * j;
      const int row = idx >> 7;
      const int col = (idx & 127) * 4;
      *reinterpret_cast<float4*>(&sx[row][col]) = xg[idx];
    }
  }
  __syncthreads();

  f32x4 acc[3][4];
#pragma unroll
  for (int m = 0; m < 3; ++m)
#pragma unroll
    for (int nt = 0; nt < 4; ++nt)
#pragma unroll
      for (int i = 0; i < 4; ++i) acc[m][nt][i] = 0.f;

  const int kb = wv * 128;
  const int wbase = (kb + qd * 8) * 64 + ln;

  float wf[2][32];
#define LDW(kt_, m_, buf_)                                                     \
  do {                                                                         \
    const float* W_ = ((m_) == 0) ? Wq : (((m_) == 1) ? Wk : Wv);              \
    const int o_ = wbase + (kt_) * 32 * 64;                                    \
    _Pragma("unroll") for (int nt = 0; nt < 4; ++nt)                           \
      _Pragma("unroll") for (int j = 0; j < 8; ++j)                            \
        wf[buf_][nt * 8 + j] = W_[o_ + j * 64 + nt * 16];                      \
  } while (0)

  LDW(0, 0, 0);
#pragma unroll
  for (int kt = 0; kt < 4; ++kt) {
    const int k0 = kb + kt * 32;
    float xs[8];
    *reinterpret_cast<float4*>(xs) =
        *reinterpret_cast<const float4*>(&sx[ln][k0 + qd * 8]);
    *reinterpret_cast<float4*>(xs + 4) =
        *reinterpret_cast<const float4*>(&sx[ln][k0 + qd * 8 + 4]);
    ushort ah[8] __attribute__((aligned(16)));
    ushort al[8] __attribute__((aligned(16)));
#pragma unroll
    for (int j = 0; j < 8; ++j) {
      const ushort h = bf16_of(xs[j]);
      ah[j] = h;
      al[j] = bf16_of(xs[j] - f_of_bf16(h));
    }
    const short8 Ah = *reinterpret_cast<short8*>(ah);
    const short8 Al = *reinterpret_cast<short8*>(al);
#pragma unroll
    for (int m = 0; m < 3; ++m) {
      const int g = kt * 3 + m;               // compile-time (unrolled)
      const int buf = g & 1;
      if (g < 11) {
        const int gn = g + 1;
        LDW(gn / 3, gn % 3, buf ^ 1);         // prefetch next group's W fp32
      }
      const float scale = (m == 0) ? 0.125f * 1.44269504088896f : 1.0f;
#pragma unroll
      for (int nt = 0; nt < 4; ++nt) {
        ushort bh8[8] __attribute__((aligned(16)));
        ushort bl8[8] __attribute__((aligned(16)));
#pragma unroll
        for (int j = 0; j < 8; ++j) {
          const float v = wf[buf][nt * 8 + j] * scale;
          const ushort h = bf16_of(v);
          bh8[j] = h;
          bl8[j] = bf16_of(v - f_of_bf16(h));
        }
        const short8 bh = *reinterpret_cast<short8*>(bh8);
        const short8 bl = *reinterpret_cast<short8*>(bl8);
        acc[m][nt] = mfma16(Ah, bh, acc[m][nt]);
        acc[m][nt] = mfma16(Ah, bl, acc[m][nt]);
        acc[m][nt] = mfma16(Al, bh, acc[m][nt]);
      }
    }
  }
#undef LDW

  const int eidx = (qd * 4) * 64 + ln;
  __syncthreads();
  if (wv >= 2) {
    float* b = mb + (size_t)(wv - 2) * 3072;
#pragma unroll
    for (int m = 0; m < 3; ++m)
#pragma unroll
      for (int nt = 0; nt < 4; ++nt)
#pragma unroll
        for (int r = 0; r < 4; ++r)
          b[m * 1024 + eidx + r * 64 + nt * 16] = acc[m][nt][r];
  }
  __syncthreads();
  if (wv < 2) {
    const float* b = mb + (size_t)wv * 3072;
#pragma unroll
    for (int m = 0; m < 3; ++m)
#pragma unroll
      for (int nt = 0; nt < 4; ++nt)
#pragma unroll
        for (int r = 0; r < 4; ++r)
          acc[m][nt][r] += b[m * 1024 + eidx + r * 64 + nt * 16];
  }
  __syncthreads();
  if (wv == 1) {
#pragma unroll
    for (int m = 0; m < 3; ++m)
#pragma unroll
      for (int nt = 0; nt < 4; ++nt)
#pragma unroll
        for (int r = 0; r < 4; ++r)
          mb[m * 1024 + eidx + r * 64 + nt * 16] = acc[m][nt][r];
  }
  __syncthreads();
  if (wv == 0) {
#pragma unroll
    for (int m = 0; m < 3; ++m)
#pragma unroll
      for (int nt = 0; nt < 4; ++nt)
#pragma unroll
        for (int r = 0; r < 4; ++r)
          acc[m][nt][r] += mb[m * 1024 + eidx + r * 64 + nt * 16];

    // ---- fp16 output encoding ----
#pragma unroll
    for (int nt = 0; nt < 4; ++nt)
#pragma unroll
      for (int r = 0; r < 4; ++r) {
        const int row = rb + qd * 4 + r;
        const int col = nt * 16 + ln;
        // Q: hi + lo fp16 (exact to 2^-22)
        const float vq = acc[0][nt][r];
        const ushort qh = f16b(vq);
        Qh[(size_t)row * DH + col] = qh;
        Ql[(size_t)row * DH + col] = f16b(vq - f_of_f16(qh));
        // K: hi only fp16
        Kh[(size_t)row * DH + col] = f16b(acc[1][nt][r]);
      }
#pragma unroll
    for (int nt = 0; nt < 4; ++nt) {
      ushort vp[4] __attribute__((aligned(8)));
#pragma unroll
      for (int r = 0; r < 4; ++r) vp[r] = f16b(acc[2][nt][r]);
      *reinterpret_cast<us4*>(Vt + (size_t)(nt * 16 + ln) * SEQ + rb + qd * 4) =
          *reinterpret_cast<us4*>(vp);
    }
  }
}

// ---------------------------------------------------------------------------
// Kernel 2 (flash v11): R16 structure (3-buffer, lgkm barrier, full unroll)
// with fp16 2-term QK: S = Kh.(Qh+Ql) -- 32 QK MFMA/iter (was 48), Kl
// GONE (LDS 72->48 KB, K reads/stores halved, Kl fetch gone).  P/V/O fp16.
// T5 setprio(1) around MFMA clusters.
// ---------------------------------------------------------------------------
__global__ __launch_bounds__(256, 2) void flash_kernel(
    const ushort* __restrict__ Qh, const ushort* __restrict__ Ql,
    const ushort* __restrict__ Kh, const ushort* __restrict__ Vt,
    ushort* __restrict__ Opart, float* __restrict__ Mpart,
    float* __restrict__ Lpart) {
  __shared__ __attribute__((aligned(16))) ushort sKh[3][BK][LDK];  // 24 KB
  __shared__ __attribute__((aligned(16))) ushort sVt[3][DH][LDK];  // 24 KB

  const int tid  = threadIdx.x;
  const int wv   = tid >> 6;
  const int lane = tid & 63;
  const int ln   = lane & 15;
  const int qd   = lane >> 4;
  const int bid  = blockIdx.x;
  const int sg   = bid & (SG - 1);
  const int qt   = bid >> 3;            // 0..63 (128-row Q tiles)
  const int qrow0  = qt * 128 + wv * 32;   // set s adds s*16
  const int k0base = sg * CHUNK;

  const int r0 = tid >> 3, g0 = (tid & 7) * 8;
  const int r1 = r0 + 32,  g1 = g0;
  const int sr0 = slot_of(r0), sr1 = slot_of(r1);   // permuted K slots

  const ushort one_u = (ln == 0) ? (ushort)0x3C00 : (ushort)0;   // fp16 1.0
  short8 afr1;
#pragma unroll
  for (int j = 0; j < 8; ++j) afr1[j] = (short)one_u;

  short8 bqh[2][2], bql[2][2];
#pragma unroll
  for (int s = 0; s < 2; ++s)
#pragma unroll
    for (int kt = 0; kt < 2; ++kt) {
      bqh[s][kt] = *reinterpret_cast<const short8*>(
          Qh + (size_t)(qrow0 + s * 16 + ln) * DH + kt * 32 + qd * 8);
      bql[s][kt] = *reinterpret_cast<const short8*>(
          Ql + (size_t)(qrow0 + s * 16 + ln) * DH + kt * 32 + qd * 8);
    }

  f32x4 accO[2][4], accL[2];
  float m_run[2] = {-INFINITY, -INFINITY};
#pragma unroll
  for (int s = 0; s < 2; ++s) {
#pragma unroll
    for (int nt = 0; nt < 4; ++nt)
#pragma unroll
      for (int i = 0; i < 4; ++i) accO[s][nt][i] = 0.f;
#pragma unroll
    for (int i = 0; i < 4; ++i) accL[s][i] = 0.f;
  }
  const f32x4 z4 = {0.f, 0.f, 0.f, 0.f};   // persistent zero C-operand

  f32x4 accSA[2][4], accSB[2][4];          // 2-deep S pipeline

  uint4 pk0, pk1, pv0, pv1;
#define LOAD_TILES(k0_)                                                        \
  do {                                                                         \
    pk0 = *reinterpret_cast<const uint4*>(Kh + (size_t)((k0_) + r0) * DH + g0);\
    pk1 = *reinterpret_cast<const uint4*>(Kh + (size_t)((k0_) + r1) * DH + g1);\
    pv0 = *reinterpret_cast<const uint4*>(Vt + (size_t)r0 * SEQ + (k0_) + g0); \
    pv1 = *reinterpret_cast<const uint4*>(Vt + (size_t)r1 * SEQ + (k0_) + g1); \
  } while (0)
#define STORE_TILES(b_)                                                        \
  do {                                                                         \
    *reinterpret_cast<uint4*>(&sKh[b_][sr0][swz(sr0, g0)]) = pk0;              \
    *reinterpret_cast<uint4*>(&sKh[b_][sr1][swz(sr1, g1)]) = pk1;              \
    *reinterpret_cast<uint4*>(&sVt[b_][r0][swz(r0, g0)])   = pv0;              \
    *reinterpret_cast<uint4*>(&sVt[b_][r1][swz(r1, g1)])   = pv1;              \
  } while (0)

  // QK^T: S^T = Kh . (Qh + Ql) -- 4 MFMA per (nt,s).
#define QK_PHASE(ACC, b_)                                                      \
  do {                                                                         \
    __builtin_amdgcn_s_setprio(1);                                             \
    _Pragma("unroll") for (int nt = 0; nt < 4; ++nt) {                         \
      const int kr = nt * 16 + ln;                                             \
      const short8 kh0 = *reinterpret_cast<const short8*>(                     \
          &sKh[b_][kr][swz(kr, qd * 8)]);                                      \
      const short8 kh1 = *reinterpret_cast<const short8*>(                     \
          &sKh[b_][kr][swz(kr, 32 + qd * 8)]);                                 \
      _Pragma("unroll") for (int s = 0; s < 2; ++s) {                          \
        ACC[s][nt] = mfma16f(kh0, bqh[s][0], z4);                              \
        ACC[s][nt] = mfma16f(kh1, bqh[s][1], ACC[s][nt]);                      \
        ACC[s][nt] = mfma16f(kh0, bql[s][0], ACC[s][nt]);                      \
        ACC[s][nt] = mfma16f(kh1, bql[s][1], ACC[s][nt]);                      \
      }                                                                        \
    }                                                                          \
    __builtin_amdgcn_s_setprio(0);                                             \
  } while (0)

  // softmax(ACC) with defer-max + PV from buffer bc_ (all fp16 frags).
#define SMPV_PHASE(ACC, bc_)                                                   \
  do {                                                                         \
    uint pkd[2][4][2];                                                         \
    _Pragma("unroll") for (int s = 0; s < 2; ++s) {                            \
      float tmax = fmaxf(fmaxf(ACC[s][0][0], ACC[s][0][1]), ACC[s][0][2]);     \
      tmax = fmaxf(fmaxf(tmax, ACC[s][0][3]), ACC[s][1][0]);                   \
      tmax = fmaxf(fmaxf(tmax, ACC[s][1][1]), ACC[s][1][2]);                   \
      tmax = fmaxf(fmaxf(tmax, ACC[s][1][3]), ACC[s][2][0]);                   \
      tmax = fmaxf(fmaxf(tmax, ACC[s][2][1]), ACC[s][2][2]);                   \
      tmax = fmaxf(fmaxf(tmax, ACC[s][2][3]), ACC[s][3][0]);                   \
      tmax = fmaxf(fmaxf(tmax, ACC[s][3][1]), ACC[s][3][2]);                   \
      tmax = fmaxf(tmax, ACC[s][3][3]);                                        \
      tmax = fmaxf(tmax, __shfl_xor(tmax, 16));                                \
      tmax = fmaxf(tmax, __shfl_xor(tmax, 32));                                \
      if (tmax > m_run[s] + 8.f) {      /* T13: rescale only on real growth */ \
        const float mnew  = fmaxf(m_run[s], tmax);                             \
        const float alpha = exp2f(m_run[s] - mnew);                            \
        m_run[s] = mnew;                                                       \
        _Pragma("unroll") for (int nt = 0; nt < 4; ++nt)                       \
          _Pragma("unroll") for (int i = 0; i < 4; ++i)                        \
            accO[s][nt][i] *= alpha;                                           \
        accL[s][0] *= alpha;                                                   \
      }                                                                        \
      const float mr = m_run[s];                                               \
      _Pragma("unroll") for (int nt = 0; nt < 4; ++nt) {                       \
        pkd[s][nt][0] = pack_f16(exp2f(ACC[s][nt][0] - mr),                    \
                                 exp2f(ACC[s][nt][1] - mr));                   \
        pkd[s][nt][1] = pack_f16(exp2f(ACC[s][nt][2] - mr),                    \
                                 exp2f(ACC[s][nt][3] - mr));                   \
      }                                                                        \
    }                                                                          \
    __builtin_amdgcn_s_setprio(1);                                             \
    _Pragma("unroll") for (int kt2 = 0; kt2 < 2; ++kt2) {                      \
      short8 pfrag[2];                                                         \
      _Pragma("unroll") for (int s = 0; s < 2; ++s) {                          \
        uint4 du;                                                              \
        du.x = pkd[s][kt2][0];                                                 \
        du.y = pkd[s][kt2][1];                                                 \
        du.z = pkd[s][kt2 + 2][0];                                             \
        du.w = pkd[s][kt2 + 2][1];                                             \
        pfrag[s] = *reinterpret_cast<short8*>(&du);                            \
      }                                                                        \
      _Pragma("unroll") for (int nt2 = 0; nt2 < 4; ++nt2) {                    \
        const int vr = nt2 * 16 + ln;                                          \
        const short8 vA = *reinterpret_cast<const short8*>(                    \
            &sVt[bc_][vr][swz(vr, kt2 * 32 + qd * 8)]);                        \
        accO[0][nt2] = mfma16f(vA, pfrag[0], accO[0][nt2]);                    \
        accO[1][nt2] = mfma16f(vA, pfrag[1], accO[1][nt2]);                    \
      }                                                                        \
      accL[0] = mfma16f(afr1, pfrag[0], accL[0]);                              \
      accL[1] = mfma16f(afr1, pfrag[1], accL[1]);                              \
    }                                                                          \
    __builtin_amdgcn_s_setprio(0);                                             \
  } while (0)

  // ----- prologue: stage tiles 0,1; hold tile 2 in regs; QK(0) -----
  LOAD_TILES(k0base);
  STORE_TILES(0);
  LOAD_TILES(k0base + BK);
  STORE_TILES(1);
  LOAD_TILES(k0base + 2 * BK);
  bar_lgkm();
  QK_PHASE(accSA, 0);

  // ----- 16 fully-unrolled bodies, compile-time buffer indices -----
#define BODY(t_, AC, AN)                                                       \
  do {                                                                         \
    if ((t_) <= NIT - 3) STORE_TILES(((t_) + 2) % 3);                          \
    if ((t_) <= NIT - 4) LOAD_TILES(k0base + ((t_) + 3) * BK);                 \
    if ((t_) <= NIT - 2) QK_PHASE(AN, ((t_) + 1) % 3);                         \
    SMPV_PHASE(AC, (t_) % 3);                                                  \
    if ((t_) <= NIT - 2) bar_lgkm();                                           \
  } while (0)

  BODY(0,  accSA, accSB);
  BODY(1,  accSB, accSA);
  BODY(2,  accSA, accSB);
  BODY(3,  accSB, accSA);
  BODY(4,  accSA, accSB);
  BODY(5,  accSB, accSA);
  BODY(6,  accSA, accSB);
  BODY(7,  accSB, accSA);
  BODY(8,  accSA, accSB);
  BODY(9,  accSB, accSA);
  BODY(10, accSA, accSB);
  BODY(11, accSB, accSA);
  BODY(12, accSA, accSB);
  BODY(13, accSB, accSA);
  BODY(14, accSA, accSB);
  BODY(15, accSB, accSA);
#undef BODY
#undef QK_PHASE
#undef SMPV_PHASE
#undef LOAD_TILES
#undef STORE_TILES

#pragma unroll
  for (int s = 0; s < 2; ++s) {
    const int qrow = qrow0 + s * 16 + ln;
    ushort* Ob = Opart + ((size_t)sg * SEQ + qrow) * DH;
#pragma unroll
    for (int nt = 0; nt < 4; ++nt) {
      ushort op[4] __attribute__((aligned(8)));
#pragma unroll
      for (int r = 0; r < 4; ++r) op[r] = f16b(accO[s][nt][r]);
      *reinterpret_cast<us4*>(Ob + nt * 16 + qd * 4) =
          *reinterpret_cast<us4*>(op);
    }
    if (qd == 0) {
      Mpart[(size_t)sg * SEQ + qrow] = m_run[s];
      Lpart[(size_t)sg * SEQ + qrow] = accL[s][0];
    }
  }
}

// ---------------------------------------------------------------------------
// Kernel 3: merge of the SG=8 seq-split partials (exp2 domain), fp16 in.
// ---------------------------------------------------------------------------
__global__ __launch_bounds__(256) void merge_kernel(
    const ushort* __restrict__ Opart, const float* __restrict__ Mpart,
    const float* __restrict__ Lpart, float* __restrict__ out) {
  const int idx = blockIdx.x * 256 + threadIdx.x;   // 0 .. SEQ*16
  const int row = idx >> 4;
  const int c4  = (idx & 15) * 4;

  float m[SG];
  float M = -INFINITY;
#pragma unroll
  for (int i = 0; i < SG; ++i) {
    m[i] = Mpart[(size_t)i * SEQ + row];
    M = fmaxf(M, m[i]);
  }
  float L = 0.f;
  float a0 = 0.f, a1 = 0.f, a2 = 0.f, a3 = 0.f;
#pragma unroll
  for (int i = 0; i < SG; ++i) {
    const float w = exp2f(m[i] - M);
    L += w * Lpart[(size_t)i * SEQ + row];
    const us4 o = *reinterpret_cast<const us4*>(
        Opart + ((size_t)i * SEQ + row) * DH + c4);
    a0 += w * f_of_f16(o[0]);
    a1 += w * f_of_f16(o[1]);
    a2 += w * f_of_f16(o[2]);
    a3 += w * f_of_f16(o[3]);
  }
  const float rL = 1.0f / L;
  float4 res = make_float4(a0 * rL, a1 * rL, a2 * rL, a3 * rL);
  *reinterpret_cast<float4*>(out + (size_t)row * DH + c4) = res;
}

// ---------------------------------------------------------------------------
extern "C" void kernel_launch(void* const* d_in, const int* in_sizes, int n_in,
                              void* d_out, int out_size, void* d_ws, size_t ws_size,
                              hipStream_t stream) {
  const float* x  = (const float*)d_in[0];
  const float* Wq = (const float*)d_in[1];
  const float* Wk = (const float*)d_in[2];
  const float* Wv = (const float*)d_in[3];
  float* out = (float*)d_out;

  // workspace layout — 12.8 MB (R19: Kl eliminated).
  const size_t S64 = (size_t)SEQ * DH;        // 524288
  ushort* Qh = (ushort*)d_ws;
  ushort* Ql = Qh + S64;
  ushort* Kh = Ql + S64;
  ushort* Vt = Kh + S64;
  ushort* Op = Vt + S64;                      // [SG][SEQ][DH] fp16
  float*  Mp = (float*)(Op + (size_t)SG * S64);
  float*  Lp = Mp + (size_t)SG * SEQ;

  pgemm_kernel<<<SEQ / 16, 256, 0, stream>>>(x, Wq, Wk, Wv, Qh, Ql, Kh, Vt);
  flash_kernel<<<(SEQ / 128) * SG, 256, 0, stream>>>(Qh, Ql, Kh, Vt, Op, Mp, Lp);
  merge_kernel<<<(SEQ * 16) / 256, 256, 0, stream>>>(Op, Mp, Lp, out);
}